// Round 6
// baseline (713.567 us; speedup 1.0000x reference)
//
#include <hip/hip_runtime.h>

// AlphaNet: B=65536, F=8, T=60 = 6 windows x 10.
// R6 = R5 with kT fixed (R5 transposed only 16/64 samples per tile -> poison).
//   kT : xb[B][480] -> xbT[sblk][480][64]  (per-block contiguous 120KB)
//   kA : block=384thr=6 waves (wave=window, lane=sample). Load all 80 vals of
//        the window up front (one burst), compute 76 channel values, DPP-flush
//        sum/sumsq, LDS flip-max for group max3, waves 0/3 flush max stats.
//   k2 : BN params + fold into weights: w1s[608][30], c0[30]
//        (max3(bn(h)) = sc*max3raw+sh valid since sc=g*rsqrt(var)>=0).
//   kB : same structure; each channel value -> a[30] += v*w1s_row (s_load rows),
//        waves 0/3 add max rows, LDS combine, wave0 does relu-dot-w2 -> out.
// ws floats: [0,304) stats | [304,336) c0 | [336,18576) w1s | [18688,..) xbT

#define NB 65536
#define EPS_F    1e-8f
#define BN_EPS_F 1e-5f

__device__ __forceinline__ float frcp(float x) { return __builtin_amdgcn_rcpf(x); }

template<int Ctrl, int RowMask>
__device__ __forceinline__ float dpp_mov0(float v) {
  return __int_as_float(__builtin_amdgcn_update_dpp(
      0, __float_as_int(v), Ctrl, RowMask, 0xf, true));
}
// wave64 sum; result valid in lane 63. VALU-only.
__device__ __forceinline__ float wave_sum64(float v) {
  v += dpp_mov0<0x111, 0xf>(v);
  v += dpp_mov0<0x112, 0xf>(v);
  v += dpp_mov0<0x114, 0xf>(v);
  v += dpp_mov0<0x118, 0xf>(v);
  v += dpp_mov0<0x142, 0xa>(v);
  v += dpp_mov0<0x143, 0xc>(v);
  return v;
}

// order-preserving float<->uint map (no NaNs in data)
__device__ __forceinline__ unsigned flipf(float v) {
  unsigned f = __float_as_uint(v);
  return (f & 0x80000000u) ? ~f : (f | 0x80000000u);
}
__device__ __forceinline__ float unflipf(unsigned k) {
  return __uint_as_float((k & 0x80000000u) ? (k ^ 0x80000000u) : ~k);
}

__host__ __device__ constexpr int PIDX(int i, int j) { return i*7 - i*(i-1)/2 + (j - i - 1); }

// ---------------- kT: xb[B][480] -> xbT[sblk][480][64] ----------------
__global__ void __launch_bounds__(256)
kT(const float* __restrict__ xb, float* __restrict__ xbT) {
  __shared__ float tile[60][65];
  const int sb = blockIdx.x;                    // 64-sample tile
  const float* src = xb + (size_t)sb * 64 * 480;
  float* dstb = xbT + (size_t)sb * 480 * 64;
  #pragma unroll 1
  for (int c = 0; c < 8; ++c) {                 // 60-channel chunks
    #pragma unroll
    for (int k = 0; k < 15; ++k) {              // 15*256 = 3840 = 64 samp * 60 ch
      int idx = k * 256 + threadIdx.x;
      int i = idx / 60, j = idx - i * 60;       // i: sample 0..63, j: channel 0..59
      tile[j][i] = src[(size_t)i * 480 + c * 60 + j];
    }
    __syncthreads();
    float* dst = dstb + (size_t)(c * 60) * 64;
    #pragma unroll
    for (int k = 0; k < 15; ++k) {
      int idx = k * 256 + threadIdx.x;
      int row = idx >> 6, ii = idx & 63;        // row: channel 0..59, ii: sample
      dst[(size_t)row * 64 + ii] = tile[row][ii];
    }
    __syncthreads();
  }
}

// ---- shared per-window feature computation ----
template <typename EmitFn>
__device__ __forceinline__ void window_compute(
    const float* __restrict__ base /* xbT + blk*480*64 + lane */, int w,
    const float* __restrict__ cw, const float* __restrict__ cb, EmitFn&& emit) {
  float x[8][10];
  #pragma unroll
  for (int f = 0; f < 8; ++f) {
    const float* pf = base + (size_t)(f * 60 + w * 10) * 64;
    #pragma unroll
    for (int t = 0; t < 10; ++t) x[f][t] = pf[(size_t)t * 64];
  }
  float mu[8], sd[8];
  #pragma unroll
  for (int f = 0; f < 8; ++f) {
    float sm = 0.f, sq = 0.f, ws = 0.f;
    float cv0 = cb[0], cv1 = cb[1], cv2 = cb[2], cv3 = cb[3];
    #pragma unroll
    for (int t = 0; t < 10; ++t) {
      float xv = x[f][t];
      sm += xv;
      sq = fmaf(xv, xv, sq);
      ws = fmaf(xv, (float)(t + 1) * (1.0f / 55.0f), ws);
      cv0 = fmaf(xv, cw[0 * 10 + t], cv0);
      cv1 = fmaf(xv, cw[1 * 10 + t], cv1);
      cv2 = fmaf(xv, cw[2 * 10 + t], cv2);
      cv3 = fmaf(xv, cw[3 * 10 + t], cv3);
    }
    mu[f] = sm * 0.1f;
    sd[f] = sqrtf(fmaf(-mu[f], mu[f], sq * 0.1f) + EPS_F);
    emit(28 + f, mu[f] * frcp(sd[f] + EPS_F));
    emit(36 + f, ws);
    emit(44 + 0 * 8 + f, cv0);
    emit(44 + 1 * 8 + f, cv1);
    emit(44 + 2 * 8 + f, cv2);
    emit(44 + 3 * 8 + f, cv3);
  }
  #pragma unroll
  for (int i = 0; i < 8; ++i)
    #pragma unroll
    for (int j = i + 1; j < 8; ++j) {
      float dot = 0.f;
      #pragma unroll
      for (int t = 0; t < 10; ++t) dot = fmaf(x[i][t], x[j][t], dot);
      float cov = fmaf(-mu[i], mu[j], dot * 0.1f);
      emit(PIDX(i, j), cov * frcp(fmaf(sd[i], sd[j], EPS_F)));
    }
}

// ---------------- kA: batch statistics ----------------
// stats: [0,76) sum | [76,152) sumsq | [152,228) sum max3 | [228,304) sumsq max3
__global__ void __launch_bounds__(384)
kA(const float* __restrict__ xbT, const float* __restrict__ cw,
   const float* __restrict__ cb, float* __restrict__ stats) {
  const int tid  = threadIdx.x;
  const int wave = tid >> 6, lane = tid & 63;
  const int w    = __builtin_amdgcn_readfirstlane(wave);  // window 0..5
  const int g    = (w >= 3) ? 1 : 0;                      // max3 group
  const bool ll  = (lane == 63);

  __shared__ float acc[304];
  __shared__ unsigned maxk[2][76][64];
  for (int i = tid; i < 304; i += 384) acc[i] = 0.f;
  for (int i = tid; i < 2 * 76 * 64; i += 384) (&maxk[0][0][0])[i] = 0u;
  __syncthreads();

  const float* base = xbT + (size_t)blockIdx.x * 480 * 64 + lane;
  window_compute(base, w, cw, cb, [&](int ch, float v) {
    float s_ = wave_sum64(v);
    float q_ = wave_sum64(v * v);
    if (ll) { atomicAdd(&acc[ch], s_); atomicAdd(&acc[76 + ch], q_); }
    atomicMax(&maxk[g][ch][lane], flipf(v));
  });
  __syncthreads();

  if (w == 0 || w == 3) {
    #pragma unroll 4
    for (int ch = 0; ch < 76; ++ch) {
      float v = unflipf(maxk[g][ch][lane]);
      float s_ = wave_sum64(v);
      float q_ = wave_sum64(v * v);
      if (ll) { atomicAdd(&acc[152 + ch], s_); atomicAdd(&acc[228 + ch], q_); }
    }
  }
  __syncthreads();
  for (int i = tid; i < 304; i += 384) atomicAdd(&stats[i], acc[i]);
}

// ---------------- k2: BN params + weight fold ----------------
__global__ void k2(const float* __restrict__ stats,
    const float* __restrict__ bn1g, const float* __restrict__ bn1b,
    const float* __restrict__ bn4g, const float* __restrict__ bn4b,
    const float* __restrict__ bn6g, const float* __restrict__ bn6b,
    const float* __restrict__ bn9g, const float* __restrict__ bn9b,
    const float* __restrict__ bnmg, const float* __restrict__ bnmb,
    const float* __restrict__ w1, const float* __restrict__ b1,
    float* __restrict__ w1s, float* __restrict__ c0) {
  const int r = blockIdx.x;       // 0..607
  const int j = threadIdx.x;      // j<30 active
  const int c = (r < 456) ? (r / 6) : ((r - 456) >> 1);
  float g, b;
  if      (c < 28) { g = bn1g[c];    b = bn1b[c];    }
  else if (c < 36) { g = bn4g[c-28]; b = bn4b[c-28]; }
  else if (c < 44) { g = bn6g[c-36]; b = bn6b[c-36]; }
  else             { g = bn9g[c-44]; b = bn9b[c-44]; }
  const float in1 = 1.0f / (65536.0f * 6.0f);
  const float in2 = 1.0f / (65536.0f * 2.0f);
  float mean = stats[c] * in1;
  float var  = stats[76 + c] * in1 - mean * mean;
  float sc1  = g * rsqrtf(var + BN_EPS_F);
  float sh1  = b - mean * sc1;
  float sc, cst;
  if (r < 456) { sc = sc1; cst = sh1; }
  else {
    float mmr  = stats[152 + c] * in2;
    float vmr  = stats[228 + c] * in2 - mmr * mmr;
    float meanm = sc1 * mmr + sh1;
    float varm  = sc1 * sc1 * vmr;
    float scm = bnmg[c] * rsqrtf(varm + BN_EPS_F);
    float shm = bnmb[c] - meanm * scm;
    sc = sc1 * scm; cst = fmaf(scm, sh1, shm);
  }
  if (j < 30) {
    float wv = w1[j * 608 + r];
    w1s[r * 30 + j] = sc * wv;
    float ca = cst * wv;
    if (r == 0) ca += b1[j];
    atomicAdd(&c0[j], ca);
  }
}

// ---------------- kB: features + MLP + output ----------------
__global__ void __launch_bounds__(384)
kB(const float* __restrict__ xbT, const float* __restrict__ cw,
   const float* __restrict__ cb, const float* __restrict__ w1s,
   const float* __restrict__ c0, const float* __restrict__ w2,
   const float* __restrict__ b2, float* __restrict__ out) {
  const int tid  = threadIdx.x;
  const int wave = tid >> 6, lane = tid & 63;
  const int w    = __builtin_amdgcn_readfirstlane(wave);  // window 0..5
  const int g    = (w >= 3) ? 1 : 0;

  __shared__ unsigned maxk[2][76][64];
  __shared__ float comb[64][31];
  for (int i = tid; i < 2 * 76 * 64; i += 384) (&maxk[0][0][0])[i] = 0u;
  for (int i = tid; i < 64 * 31; i += 384) (&comb[0][0])[i] = 0.f;
  __syncthreads();

  const float* base = xbT + (size_t)blockIdx.x * 480 * 64 + lane;
  float a[30];
  #pragma unroll
  for (int j = 0; j < 30; ++j) a[j] = 0.f;

  window_compute(base, w, cw, cb, [&](int ch, float v) {
    const float* wr = w1s + (ch * 6 + w) * 30;       // wave-uniform -> s_load
    #pragma unroll
    for (int j = 0; j < 30; ++j) a[j] = fmaf(v, wr[j], a[j]);
    atomicMax(&maxk[g][ch][lane], flipf(v));
  });
  __syncthreads();

  if (w == 0 || w == 3) {
    #pragma unroll 4
    for (int ch = 0; ch < 76; ++ch) {
      float v = unflipf(maxk[g][ch][lane]);
      const float* wr = w1s + (456 + ch * 2 + g) * 30;
      #pragma unroll
      for (int j = 0; j < 30; ++j) a[j] = fmaf(v, wr[j], a[j]);
    }
  }
  #pragma unroll
  for (int j = 0; j < 30; ++j) atomicAdd(&comb[lane][j], a[j]);
  __syncthreads();

  if (wave == 0) {
    float t = b2[0];
    #pragma unroll
    for (int j = 0; j < 30; ++j)
      t = fmaf(w2[j], fmaxf(comb[lane][j] + c0[j], 0.f), t);
    out[(size_t)blockIdx.x * 64 + lane] = t;
  }
}

// ================= launch =================

extern "C" void kernel_launch(void* const* d_in, const int* in_sizes, int n_in,
                              void* d_out, int out_size, void* d_ws, size_t ws_size,
                              hipStream_t stream) {
  (void)in_sizes; (void)n_in; (void)out_size; (void)ws_size;
  const float* xb   = (const float*)d_in[0];
  const float* cw   = (const float*)d_in[1];
  const float* cb   = (const float*)d_in[2];
  const float* bn1g = (const float*)d_in[3];
  const float* bn1b = (const float*)d_in[4];
  const float* bn4g = (const float*)d_in[5];
  const float* bn4b = (const float*)d_in[6];
  const float* bn6g = (const float*)d_in[7];
  const float* bn6b = (const float*)d_in[8];
  const float* bn9g = (const float*)d_in[9];
  const float* bn9b = (const float*)d_in[10];
  const float* bnmg = (const float*)d_in[11];
  const float* bnmb = (const float*)d_in[12];
  const float* w1   = (const float*)d_in[13];
  const float* b1   = (const float*)d_in[14];
  const float* w2   = (const float*)d_in[15];
  const float* b2   = (const float*)d_in[16];

  float* out   = (float*)d_out;
  float* ws    = (float*)d_ws;
  float* stats = ws;           // 304
  float* c0    = ws + 304;     // 32
  float* w1s   = ws + 336;     // 608*30 -> ends 18576
  float* xbT   = ws + 18688;   // 480*65536 tiled [sblk][480][64]

  hipMemsetAsync(ws, 0, 336 * sizeof(float), stream);
  kT<<<1024, 256, 0, stream>>>(xb, xbT);
  kA<<<1024, 384, 0, stream>>>(xbT, cw, cb, stats);
  k2<<<608, 32, 0, stream>>>(stats, bn1g, bn1b, bn4g, bn4b, bn6g, bn6b,
                             bn9g, bn9b, bnmg, bnmb, w1, b1, w1s, c0);
  kB<<<1024, 384, 0, stream>>>(xbT, cw, cb, w1s, c0, w2, b2, out);
}